// Round 4
// baseline (93.212 us; speedup 1.0000x reference)
//
#include <hip/hip_runtime.h>
#include <hip/hip_bf16.h>

#define N_ 8192
#define D_ 256
#define BM 128
#define NB (N_ / BM)            // 64
#define NT (NB * (NB + 1) / 2)  // 2080 triangular tiles
#define KSTEPS (D_ / 32)        // 8

typedef __bf16 bf16x8 __attribute__((ext_vector_type(8)));
typedef float f32x4 __attribute__((ext_vector_type(4)));

// ---------------- fp32 -> bf16 convert (+ zero the accumulators) ----------------
__global__ void cvt_kernel(const float4* __restrict__ in, ushort4* __restrict__ out, int n4,
                           double* __restrict__ accd) {
  int i = blockIdx.x * blockDim.x + threadIdx.x;
  if (blockIdx.x == 0 && threadIdx.x < 128) accd[threadIdx.x] = 0.0;
  if (i >= n4) return;
  float4 v = in[i];
  union { __hip_bfloat16 h[4]; ushort4 u; } t;
  t.h[0] = __float2bfloat16(v.x);
  t.h[1] = __float2bfloat16(v.y);
  t.h[2] = __float2bfloat16(v.z);
  t.h[3] = __float2bfloat16(v.w);
  out[i] = t.u;
}

// ws accumulator layout (doubles):
//  [32][3] slots {pos_cnt, pos_sim_sum, neg_sim_sum}   (0..95)
//  [96..99] lastrow {lp_sum, lp_cnt, ln_sum, ln_cnt}
//
// No LDS staging: Xb (4 MB) is L2-resident per XCD. Fragments are loaded
// directly from global, fully coalesced, zero barriers in the K-loop.
__global__ __launch_bounds__(256, 4) void simloss_kernel(
    const __hip_bfloat16* __restrict__ Xb, const int* __restrict__ tg,
    double* __restrict__ accd) {
  // ---- triangular tile decode ----
  const int t = blockIdx.x;
  int bi = (int)(((2.0f * NB + 1.0f) -
                  sqrtf((2.0f * NB + 1.0f) * (2.0f * NB + 1.0f) - 8.0f * (float)t)) * 0.5f);
  if (bi < 0) bi = 0;
  if (bi > NB - 1) bi = NB - 1;
  while (((bi + 1) * NB - ((bi + 1) * bi) / 2) <= t) ++bi;
  while ((bi * NB - (bi * (bi - 1)) / 2) > t) --bi;
  const int bj = bi + (t - (bi * NB - (bi * (bi - 1)) / 2));

  const int tid = threadIdx.x;
  const int lane = tid & 63, wv = tid >> 6;
  const int wr = wv >> 1, wc = wv & 1;  // wave -> 64x64 sub-tile of 128x128
  const int rowA0 = bi * BM, rowB0 = bj * BM;

  // ---- fragment base pointers: A row = rowA0+wr*64+m*16+fr, cols sl*8.. ----
  const int fr = lane & 15, sl = lane >> 4;
  const __hip_bfloat16* pA[4];
  const __hip_bfloat16* pB[4];
#pragma unroll
  for (int m = 0; m < 4; ++m)
    pA[m] = Xb + (size_t)(rowA0 + wr * 64 + m * 16 + fr) * D_ + sl * 8;
#pragma unroll
  for (int n = 0; n < 4; ++n)
    pB[n] = Xb + (size_t)(rowB0 + wc * 64 + n * 16 + fr) * D_ + sl * 8;

  f32x4 acc[4][4] = {};

#pragma unroll
  for (int kt = 0; kt < KSTEPS; ++kt) {
    bf16x8 af[4], bfr[4];
#pragma unroll
    for (int m = 0; m < 4; ++m) af[m] = *(const bf16x8*)(pA[m] + kt * 32);
#pragma unroll
    for (int n = 0; n < 4; ++n) bfr[n] = *(const bf16x8*)(pB[n] + kt * 32);
#pragma unroll
    for (int m = 0; m < 4; ++m)
#pragma unroll
      for (int n = 0; n < 4; ++n)
        acc[m][n] = __builtin_amdgcn_mfma_f32_16x16x32_bf16(af[m], bfr[n], acc[m][n], 0, 0, 0);
  }

  // ---- epilogue: C/D layout col=lane&15, row=(lane>>4)*4+reg  [guide §3] ----
  const int cRow = sl * 4, cCol = fr;
  int tj[4], ti[4][4];
#pragma unroll
  for (int n = 0; n < 4; ++n) tj[n] = tg[rowB0 + wc * 64 + n * 16 + cCol];
#pragma unroll
  for (int m = 0; m < 4; ++m)
#pragma unroll
    for (int r = 0; r < 4; ++r) ti[m][r] = tg[rowA0 + wr * 64 + m * 16 + cRow + r];

  float pc = 0.f, ps = 0.f, ns = 0.f;
#pragma unroll
  for (int m = 0; m < 4; ++m)
#pragma unroll
    for (int n = 0; n < 4; ++n)
#pragma unroll
      for (int r = 0; r < 4; ++r) {
        float s = acc[m][n][r];
        bool same = (ti[m][r] == tj[n]);
        if (same & (s < 0.9f)) { pc += 1.0f; ps += s; }
        if ((!same) & (s > 0.5f)) { ns += s; }
      }

  // ---- last-row (row 8191) stats: column 8191 lives at bj=63, wc=1, n=3, cCol=15 ----
  if (bj == NB - 1 && wc == 1 && cCol == 15) {
    const int tlast = tj[3];  // tg[8191]
    float lps = 0.f, lns = 0.f, lpc = 0.f, lnc = 0.f;
#pragma unroll
    for (int m = 0; m < 4; ++m)
#pragma unroll
      for (int r = 0; r < 4; ++r) {
        float s = acc[m][3][r];
        bool same = (ti[m][r] == tlast);
        if (same && s < 1.0f) { lps += s; lpc += 1.f; }
        if (!same) { lns += s; lnc += 1.f; }
      }
    atomicAdd(&accd[96], (double)lps);
    atomicAdd(&accd[97], (double)lpc);
    atomicAdd(&accd[98], (double)lns);
    atomicAdd(&accd[99], (double)lnc);
  }

  // ---- block reduction + per-slot atomics ----
#pragma unroll
  for (int off = 32; off > 0; off >>= 1) {
    pc += __shfl_down(pc, off);
    ps += __shfl_down(ps, off);
    ns += __shfl_down(ns, off);
  }
  __shared__ float red[12];
  if (lane == 0) { red[0 + wv] = pc; red[4 + wv] = ps; red[8 + wv] = ns; }
  __syncthreads();
  if (tid == 0) {
    double w = (bi == bj) ? 1.0 : 2.0;  // off-diagonal tiles count twice
    double* slot = accd + (blockIdx.x & 31) * 3;
    atomicAdd(&slot[0], w * (double)(red[0] + red[1] + red[2] + red[3]));
    atomicAdd(&slot[1], w * (double)(red[4] + red[5] + red[6] + red[7]));
    atomicAdd(&slot[2], w * (double)(red[8] + red[9] + red[10] + red[11]));
  }
}

// ---------------- finalize ----------------
__global__ void finalize_kernel(const double* __restrict__ accd, float* __restrict__ out) {
  double pc = 0.0, ps = 0.0, ns = 0.0;
#pragma unroll
  for (int i = 0; i < 32; ++i) {
    pc += accd[i * 3 + 0];
    ps += accd[i * 3 + 1];
    ns += accd[i * 3 + 2];
  }
  double loss = (pc - ps + ns) / (double)N_;
  out[0] = (float)loss;
  out[1] = 0.0f;  // prec: reference never increments c
  out[2] = (float)(accd[96] / fmax(accd[97], 1.0));
  out[3] = (float)(accd[98] / fmax(accd[99], 1.0));
}

extern "C" void kernel_launch(void* const* d_in, const int* in_sizes, int n_in,
                              void* d_out, int out_size, void* d_ws, size_t ws_size,
                              hipStream_t stream) {
  const float* X = (const float*)d_in[0];
  const int* tg = (const int*)d_in[1];
  float* out = (float*)d_out;
  double* accd = (double*)d_ws;
  __hip_bfloat16* Xb = (__hip_bfloat16*)((char*)d_ws + 1024);

  int n4 = N_ * D_ / 4;
  cvt_kernel<<<(n4 + 255) / 256, 256, 0, stream>>>((const float4*)X, (ushort4*)Xb, n4, accd);

  simloss_kernel<<<NT, 256, 0, stream>>>(Xb, tg, accd);

  finalize_kernel<<<1, 1, 0, stream>>>(accd, out);
}

// Round 5
// 39.986 us; speedup vs baseline: 2.3311x; 2.3311x over previous
//
#include <hip/hip_runtime.h>
#include <hip/hip_bf16.h>

#define N_ 8192
#define D_ 256
#define BM 128
#define BK 32
#define NB (N_ / BM)            // 64
#define NT (NB * (NB + 1) / 2)  // 2080 triangular tiles (2080 % 8 == 0)
#define KSTEPS (D_ / BK)        // 8

typedef __bf16 bf16x8 __attribute__((ext_vector_type(8)));
typedef float f32x4 __attribute__((ext_vector_type(4)));

// ---------------- fp32 -> bf16 convert (+ zero the accumulators) ----------------
__global__ void cvt_kernel(const float4* __restrict__ in, ushort4* __restrict__ out, int n4,
                           double* __restrict__ accd) {
  int i = blockIdx.x * blockDim.x + threadIdx.x;
  if (blockIdx.x == 0 && threadIdx.x < 128) accd[threadIdx.x] = 0.0;
  if (i >= n4) return;
  float4 v = in[i];
  union { __hip_bfloat16 h[4]; ushort4 u; } t;
  t.h[0] = __float2bfloat16(v.x);
  t.h[1] = __float2bfloat16(v.y);
  t.h[2] = __float2bfloat16(v.z);
  t.h[3] = __float2bfloat16(v.w);
  out[i] = t.u;
}

// ws accumulator layout (doubles):
//  [32][3] slots {pos_cnt, pos_sim_sum, neg_sim_sum}   (0..95)
//  [96..99] lastrow {lp_sum, lp_cnt, ln_sum, ln_cnt}
//
// Triple-buffered LDS pipeline, counted vmcnt across raw s_barriers (T3/T4):
// prefetch depth 2; the per-step __syncthreads vmcnt(0) drain of R3 is gone.
__global__ __launch_bounds__(256, 3) void simloss_kernel(
    const __hip_bfloat16* __restrict__ Xb, const int* __restrict__ tg,
    double* __restrict__ accd) {
  __shared__ __align__(16) char lds[3 * 16384];  // buf b: A at b*16384, B at +8192

  // ---- XCD-chunked bijective swizzle (T1): 2080 = 8 * 260 ----
  const int t0 = blockIdx.x;
  const int t = (t0 & 7) * (NT / 8) + (t0 >> 3);

  // ---- triangular tile decode ----
  int bi = (int)(((2.0f * NB + 1.0f) -
                  sqrtf((2.0f * NB + 1.0f) * (2.0f * NB + 1.0f) - 8.0f * (float)t)) * 0.5f);
  if (bi < 0) bi = 0;
  if (bi > NB - 1) bi = NB - 1;
  while (((bi + 1) * NB - ((bi + 1) * bi) / 2) <= t) ++bi;
  while ((bi * NB - (bi * (bi - 1)) / 2) > t) --bi;
  const int bj = bi + (t - (bi * NB - (bi * (bi - 1)) / 2));

  const int tid = threadIdx.x;
  const int lane = tid & 63, wv = tid >> 6;
  const int wr = wv >> 1, wc = wv & 1;  // wave -> 64x64 sub-tile
  const int rowA0 = bi * BM, rowB0 = bj * BM;

  // ---- staging constants: chunk c -> row=c>>2, slot=c&3, srcslot=slot^((row>>1)&3)
  const int c0 = (wv * 2 + 0) * 64 + lane;
  const int c1 = (wv * 2 + 1) * 64 + lane;
  const int r0 = c0 >> 2, s0 = (c0 & 3) ^ ((r0 >> 1) & 3);
  const int r1 = c1 >> 2, s1 = (c1 & 3) ^ ((r1 >> 1) & 3);
  const __hip_bfloat16* gA0 = Xb + (size_t)(rowA0 + r0) * D_ + s0 * 8;
  const __hip_bfloat16* gA1 = Xb + (size_t)(rowA0 + r1) * D_ + s1 * 8;
  const __hip_bfloat16* gB0 = Xb + (size_t)(rowB0 + r0) * D_ + s0 * 8;
  const __hip_bfloat16* gB1 = Xb + (size_t)(rowB0 + r1) * D_ + s1 * 8;

#define GLDS(g, l) \
  __builtin_amdgcn_global_load_lds((const __attribute__((address_space(1))) void*)(g), \
                                   (__attribute__((address_space(3))) void*)(l), 16, 0, 0)
  // fixed issue order A0,A1,B0,B1 -> 4 vmcnt ops per tile, tile k = ops [4k,4k+4)
#define STAGE(buf, kt)                                    \
  do {                                                    \
    char* base = lds + (buf) * 16384;                     \
    GLDS(gA0 + (kt) * BK, base + c0 * 16);                \
    GLDS(gA1 + (kt) * BK, base + c1 * 16);                \
    GLDS(gB0 + (kt) * BK, base + 8192 + c0 * 16);         \
    GLDS(gB1 + (kt) * BK, base + 8192 + c1 * 16);         \
  } while (0)

  // ---- fragment-read constants (swizzled read slot) ----
  const int fr = lane & 15, sl = lane >> 4;
  const int rswz = sl ^ ((fr >> 1) & 3);
  const int aoff = (wr * 64 + fr) * 64 + rswz * 16;  // bytes within A half
  const int boff = (wc * 64 + fr) * 64 + rswz * 16;  // bytes within B half

  f32x4 acc[4][4] = {};

  STAGE(0, 0);
  STAGE(1, 1);
  STAGE(2, 2);  // 12 ops outstanding

#pragma unroll
  for (int kt = 0; kt < KSTEPS; ++kt) {
    // wait for tile kt only: outstanding after = min(8, 28-4*kt)
    if (kt < 6)
      asm volatile("s_waitcnt vmcnt(8)" ::: "memory");
    else if (kt == 6)
      asm volatile("s_waitcnt vmcnt(4)" ::: "memory");
    else
      asm volatile("s_waitcnt vmcnt(0)" ::: "memory");
    __builtin_amdgcn_s_barrier();  // all waves' tile-kt parts visible

    const char* Ab = lds + (kt % 3) * 16384;
    const char* Bb = Ab + 8192;
    bf16x8 af[4], bfr[4];
#pragma unroll
    for (int m = 0; m < 4; ++m) af[m] = *(const bf16x8*)(Ab + aoff + m * 1024);
#pragma unroll
    for (int n = 0; n < 4; ++n) bfr[n] = *(const bf16x8*)(Bb + boff + n * 1024);
#pragma unroll
    for (int m = 0; m < 4; ++m)
#pragma unroll
      for (int n = 0; n < 4; ++n)
        acc[m][n] = __builtin_amdgcn_mfma_f32_16x16x32_bf16(af[m], bfr[n], acc[m][n], 0, 0, 0);

    asm volatile("s_waitcnt lgkmcnt(0)" ::: "memory");  // all my ds_reads retired
    __builtin_amdgcn_sched_barrier(0);                  // nothing crosses (rule #18)
    __builtin_amdgcn_s_barrier();                       // everyone done reading buf
    if (kt + 3 < KSTEPS) STAGE(kt % 3, kt + 3);         // refill freed buffer
  }
#undef STAGE
#undef GLDS

  // ---- epilogue: C/D layout col=lane&15, row=(lane>>4)*4+reg  [guide §3] ----
  const int cRow = sl * 4, cCol = fr;
  int tj[4], ti[4][4];
#pragma unroll
  for (int n = 0; n < 4; ++n) tj[n] = tg[rowB0 + wc * 64 + n * 16 + cCol];
#pragma unroll
  for (int m = 0; m < 4; ++m)
#pragma unroll
    for (int r = 0; r < 4; ++r) ti[m][r] = tg[rowA0 + wr * 64 + m * 16 + cRow + r];

  float pc = 0.f, ps = 0.f, ns = 0.f;
#pragma unroll
  for (int m = 0; m < 4; ++m)
#pragma unroll
    for (int n = 0; n < 4; ++n)
#pragma unroll
      for (int r = 0; r < 4; ++r) {
        float s = acc[m][n][r];
        bool same = (ti[m][r] == tj[n]);
        if (same & (s < 0.9f)) { pc += 1.0f; ps += s; }
        if ((!same) & (s > 0.5f)) { ns += s; }
      }

  // ---- last-row (row 8191) stats: column 8191 at bj=63, wc=1, n=3, cCol=15 ----
  if (bj == NB - 1 && wc == 1 && cCol == 15) {
    const int tlast = tj[3];  // tg[8191]
    float lps = 0.f, lns = 0.f, lpc = 0.f, lnc = 0.f;
#pragma unroll
    for (int m = 0; m < 4; ++m)
#pragma unroll
      for (int r = 0; r < 4; ++r) {
        float s = acc[m][3][r];
        bool same = (ti[m][r] == tlast);
        if (same && s < 1.0f) { lps += s; lpc += 1.f; }
        if (!same) { lns += s; lnc += 1.f; }
      }
    atomicAdd(&accd[96], (double)lps);
    atomicAdd(&accd[97], (double)lpc);
    atomicAdd(&accd[98], (double)lns);
    atomicAdd(&accd[99], (double)lnc);
  }

  // ---- block reduction + per-slot atomics ----
#pragma unroll
  for (int off = 32; off > 0; off >>= 1) {
    pc += __shfl_down(pc, off);
    ps += __shfl_down(ps, off);
    ns += __shfl_down(ns, off);
  }
  float* red = (float*)lds;  // reuse LDS; all tile traffic complete
  if (lane == 0) { red[0 + wv] = pc; red[4 + wv] = ps; red[8 + wv] = ns; }
  __syncthreads();
  if (tid == 0) {
    double w = (bi == bj) ? 1.0 : 2.0;  // off-diagonal tiles count twice
    double* slot = accd + (blockIdx.x & 31) * 3;
    atomicAdd(&slot[0], w * (double)(red[0] + red[1] + red[2] + red[3]));
    atomicAdd(&slot[1], w * (double)(red[4] + red[5] + red[6] + red[7]));
    atomicAdd(&slot[2], w * (double)(red[8] + red[9] + red[10] + red[11]));
  }
}

// ---------------- finalize ----------------
__global__ void finalize_kernel(const double* __restrict__ accd, float* __restrict__ out) {
  double pc = 0.0, ps = 0.0, ns = 0.0;
#pragma unroll
  for (int i = 0; i < 32; ++i) {
    pc += accd[i * 3 + 0];
    ps += accd[i * 3 + 1];
    ns += accd[i * 3 + 2];
  }
  double loss = (pc - ps + ns) / (double)N_;
  out[0] = (float)loss;
  out[1] = 0.0f;  // prec: reference never increments c
  out[2] = (float)(accd[96] / fmax(accd[97], 1.0));
  out[3] = (float)(accd[98] / fmax(accd[99], 1.0));
}

extern "C" void kernel_launch(void* const* d_in, const int* in_sizes, int n_in,
                              void* d_out, int out_size, void* d_ws, size_t ws_size,
                              hipStream_t stream) {
  const float* X = (const float*)d_in[0];
  const int* tg = (const int*)d_in[1];
  float* out = (float*)d_out;
  double* accd = (double*)d_ws;
  __hip_bfloat16* Xb = (__hip_bfloat16*)((char*)d_ws + 1024);

  int n4 = N_ * D_ / 4;
  cvt_kernel<<<(n4 + 255) / 256, 256, 0, stream>>>((const float4*)X, (ushort4*)Xb, n4, accd);

  simloss_kernel<<<NT, 256, 0, stream>>>(Xb, tg, accd);

  finalize_kernel<<<1, 1, 0, stream>>>(accd, out);
}